// Round 1
// baseline (253.355 us; speedup 1.0000x reference)
//
#include <hip/hip_runtime.h>
#include <hip/hip_bf16.h>

#define EPS 1e-3f

typedef __attribute__((ext_vector_type(8))) short short8;
typedef __attribute__((ext_vector_type(4))) float v4f;

__device__ __forceinline__ unsigned short f2bf(float f) {
    unsigned int u = __float_as_uint(f);
    unsigned int r = (u + 0x7fffu + ((u >> 16) & 1u)) >> 16;
    return (unsigned short)r;
}

// ---------------------------------------------------------------------------
// Prep: fold biases + BN into per-channel affine; transpose pw_kernel into
// bf16 MFMA B-fragment layout: Wt[((ntile*2+kstep)*64 + lane)*8 + j] =
//   bf16(W[k = kstep*32 + (lane>>4)*8 + j][f = ntile*16 + (lane&15)])
// ---------------------------------------------------------------------------
__global__ __launch_bounds__(256) void prep_kernel(
    const float* __restrict__ dwb,
    const float* __restrict__ g1, const float* __restrict__ b1,
    const float* __restrict__ m1, const float* __restrict__ v1,
    const float* __restrict__ pw, const float* __restrict__ pwb,
    const float* __restrict__ g2, const float* __restrict__ b2,
    const float* __restrict__ m2, const float* __restrict__ v2,
    float* __restrict__ scale1, float* __restrict__ shift1,
    float* __restrict__ s2, float* __restrict__ t2,
    unsigned short* __restrict__ Wt)
{
    int tid = threadIdx.x;
    if (tid < 64) {
        float inv = g1[tid] * rsqrtf(v1[tid] + EPS);
        scale1[tid] = inv;
        shift1[tid] = dwb[tid] * inv + b1[tid] - m1[tid] * inv;
    }
    if (tid < 128) {
        float inv = g2[tid] * rsqrtf(v2[tid] + EPS);
        s2[tid] = inv;
        t2[tid] = pwb[tid] * inv + b2[tid] - m2[tid] * inv;
    }
    #pragma unroll
    for (int i = 0; i < 32; ++i) {
        int idx   = tid * 32 + i;          // 0..8191
        int j     = idx & 7;
        int lane  = (idx >> 3) & 63;
        int kstep = (idx >> 9) & 1;
        int ntile = idx >> 10;             // 0..7
        int k = kstep * 32 + (lane >> 4) * 8 + j;
        int f = ntile * 16 + (lane & 15);
        Wt[idx] = f2bf(pw[k * 128 + f]);
    }
}

// ---------------------------------------------------------------------------
// Depthwise 3x3x3 conv (SAME, zero pad) + BN1 + ReLU -> y (bf16, NDHWC)
// block = (16 c-groups, 16 w), grid = (W/16, H, B*D)
// ---------------------------------------------------------------------------
__global__ __launch_bounds__(256) void dw_kernel_f(
    const float* __restrict__ x,
    const float* __restrict__ wgt,     // (3,3,3,1,64)
    const float* __restrict__ scale1,
    const float* __restrict__ shift1,
    unsigned short* __restrict__ y)
{
    __shared__ float wS[27 * 64];
    __shared__ float sS[64];
    __shared__ float tS[64];

    int tid = threadIdx.y * 16 + threadIdx.x;
    for (int i = tid; i < 27 * 64; i += 256) wS[i] = wgt[i];
    if (tid < 64) { sS[tid] = scale1[tid]; tS[tid] = shift1[tid]; }
    __syncthreads();

    int c0 = threadIdx.x * 4;                 // channel group base
    int w  = blockIdx.x * 16 + threadIdx.y;
    int h  = blockIdx.y;
    int bd = blockIdx.z;
    int b  = bd / 48;
    int d  = bd % 48;

    float a0 = 0.f, a1 = 0.f, a2 = 0.f, a3 = 0.f;

    #pragma unroll
    for (int dd = 0; dd < 3; ++dd) {
        int zd = d + dd - 1;
        if (zd < 0 || zd >= 48) continue;
        #pragma unroll
        for (int hh = 0; hh < 3; ++hh) {
            int zh = h + hh - 1;
            if (zh < 0 || zh >= 48) continue;
            #pragma unroll
            for (int ww = 0; ww < 3; ++ww) {
                int zw = w + ww - 1;
                if (zw < 0 || zw >= 48) continue;
                const float4 xv = *(const float4*)(x + ((((long)b * 48 + zd) * 48 + zh) * 48 + zw) * 64 + c0);
                const float4 wv = *(const float4*)(&wS[((dd * 3 + hh) * 3 + ww) * 64 + c0]);
                a0 += xv.x * wv.x;
                a1 += xv.y * wv.y;
                a2 += xv.z * wv.z;
                a3 += xv.w * wv.w;
            }
        }
    }

    float4 s = *(const float4*)(&sS[c0]);
    float4 t = *(const float4*)(&tS[c0]);
    float r0 = fmaxf(a0 * s.x + t.x, 0.f);
    float r1 = fmaxf(a1 * s.y + t.y, 0.f);
    float r2 = fmaxf(a2 * s.z + t.z, 0.f);
    float r3 = fmaxf(a3 * s.w + t.w, 0.f);

    ushort4 o;
    o.x = f2bf(r0); o.y = f2bf(r1); o.z = f2bf(r2); o.w = f2bf(r3);
    long row = (((long)b * 48 + d) * 48 + h) * 48 + w;
    *(ushort4*)(y + row * 64 + c0) = o;
}

// ---------------------------------------------------------------------------
// Pointwise GEMM: z[row][f] = relu( (sum_k y[row][k]*W[k][f]) * s2[f] + t2[f] )
// M=221184, K=64, N=128. 4 waves/block, wave = 16 rows x 128 cols.
// mfma_f32_16x16x32_bf16; A: row=lane&15, k=(lane>>4)*8+j; D: col=lane&15,
// row=(lane>>4)*4+reg.
// ---------------------------------------------------------------------------
__global__ __launch_bounds__(256) void pw_gemm(
    const unsigned short* __restrict__ y,
    const unsigned short* __restrict__ Wt,
    const float* __restrict__ s2,
    const float* __restrict__ t2,
    float* __restrict__ out)
{
    int tid  = threadIdx.x;
    int wave = tid >> 6;
    int lane = tid & 63;
    int lrow = lane & 15;
    int quad = lane >> 4;

    long row_base = (long)blockIdx.x * 64 + wave * 16;

    const short8 a0 = *(const short8*)(y + (row_base + lrow) * 64 + quad * 8);
    const short8 a1 = *(const short8*)(y + (row_base + lrow) * 64 + 32 + quad * 8);

    v4f acc[8];
    #pragma unroll
    for (int n = 0; n < 8; ++n) acc[n] = (v4f){0.f, 0.f, 0.f, 0.f};

    #pragma unroll
    for (int n = 0; n < 8; ++n) {
        short8 b0 = *(const short8*)(Wt + ((n * 2 + 0) * 64 + lane) * 8);
        short8 b1 = *(const short8*)(Wt + ((n * 2 + 1) * 64 + lane) * 8);
        acc[n] = __builtin_amdgcn_mfma_f32_16x16x32_bf16(a0, b0, acc[n], 0, 0, 0);
        acc[n] = __builtin_amdgcn_mfma_f32_16x16x32_bf16(a1, b1, acc[n], 0, 0, 0);
    }

    #pragma unroll
    for (int n = 0; n < 8; ++n) {
        int f = n * 16 + lrow;
        float s = s2[f];
        float t = t2[f];
        #pragma unroll
        for (int r = 0; r < 4; ++r) {
            long row = row_base + quad * 4 + r;
            float v = acc[n][r] * s + t;
            out[row * 128 + f] = fmaxf(v, 0.f);
        }
    }
}

// ---------------------------------------------------------------------------
extern "C" void kernel_launch(void* const* d_in, const int* in_sizes, int n_in,
                              void* d_out, int out_size, void* d_ws, size_t ws_size,
                              hipStream_t stream)
{
    const float* x   = (const float*)d_in[0];
    const float* dwk = (const float*)d_in[1];
    const float* dwb = (const float*)d_in[2];
    const float* g1  = (const float*)d_in[3];
    const float* b1  = (const float*)d_in[4];
    const float* m1  = (const float*)d_in[5];
    const float* v1  = (const float*)d_in[6];
    const float* pw  = (const float*)d_in[7];
    const float* pwb = (const float*)d_in[8];
    const float* g2  = (const float*)d_in[9];
    const float* b2  = (const float*)d_in[10];
    const float* m2  = (const float*)d_in[11];
    const float* v2  = (const float*)d_in[12];

    float* outp = (float*)d_out;

    // ws layout: [0..383] floats: scale1(64) shift1(64) s2(128) t2(128)
    //            byte 2048: Wt bf16[8192] (16 KB)
    //            byte 18432: y bf16[14,155,776] (~28.3 MB)
    float* scale1 = (float*)d_ws;
    float* shift1 = scale1 + 64;
    float* s2     = scale1 + 128;
    float* t2     = scale1 + 256;
    unsigned short* Wt = (unsigned short*)((char*)d_ws + 2048);
    unsigned short* y  = (unsigned short*)((char*)d_ws + 18432);

    hipLaunchKernelGGL(prep_kernel, dim3(1), dim3(256), 0, stream,
                       dwb, g1, b1, m1, v1, pw, pwb, g2, b2, m2, v2,
                       scale1, shift1, s2, t2, Wt);

    hipLaunchKernelGGL(dw_kernel_f, dim3(3, 48, 96), dim3(16, 16), 0, stream,
                       x, dwk, scale1, shift1, y);

    hipLaunchKernelGGL(pw_gemm, dim3(3456), dim3(256), 0, stream,
                       y, Wt, s2, t2, outp);
}

// Round 2
// 221.644 us; speedup vs baseline: 1.1431x; 1.1431x over previous
//
#include <hip/hip_runtime.h>
#include <hip/hip_bf16.h>

#define EPS 1e-3f

typedef __attribute__((ext_vector_type(8))) short short8;
typedef __attribute__((ext_vector_type(4))) float v4f;

__device__ __forceinline__ unsigned short f2bf(float f) {
    unsigned int u = __float_as_uint(f);
    unsigned int r = (u + 0x7fffu + ((u >> 16) & 1u)) >> 16;
    return (unsigned short)r;
}

// ---------------------------------------------------------------------------
// Prep: fold biases + BN into per-channel affine; transpose pw_kernel into
// bf16 MFMA B-fragment layout: Wt[((ntile*2+kstep)*64 + lane)*8 + j] =
//   bf16(W[k = kstep*32 + (lane>>4)*8 + j][f = ntile*16 + (lane&15)])
// grid = 32 blocks x 256 thr; one Wt element per thread; block 0 does affines.
// ---------------------------------------------------------------------------
__global__ __launch_bounds__(256) void prep_kernel(
    const float* __restrict__ dwb,
    const float* __restrict__ g1, const float* __restrict__ b1,
    const float* __restrict__ m1, const float* __restrict__ v1,
    const float* __restrict__ pw, const float* __restrict__ pwb,
    const float* __restrict__ g2, const float* __restrict__ b2,
    const float* __restrict__ m2, const float* __restrict__ v2,
    float* __restrict__ scale1, float* __restrict__ shift1,
    float* __restrict__ s2, float* __restrict__ t2,
    unsigned short* __restrict__ Wt)
{
    int tid = threadIdx.x;
    if (blockIdx.x == 0) {
        if (tid < 64) {
            float inv = g1[tid] * rsqrtf(v1[tid] + EPS);
            scale1[tid] = inv;
            shift1[tid] = dwb[tid] * inv + b1[tid] - m1[tid] * inv;
        }
        if (tid < 128) {
            float inv = g2[tid] * rsqrtf(v2[tid] + EPS);
            s2[tid] = inv;
            t2[tid] = pwb[tid] * inv + b2[tid] - m2[tid] * inv;
        }
    }
    int idx = blockIdx.x * 256 + tid;      // 0..8191
    int j     = idx & 7;
    int lane  = (idx >> 3) & 63;
    int kstep = (idx >> 9) & 1;
    int ntile = idx >> 10;                 // 0..7
    int k = kstep * 32 + (lane >> 4) * 8 + j;
    int f = ntile * 16 + (lane & 15);
    Wt[idx] = f2bf(pw[k * 128 + f]);
}

// ---------------------------------------------------------------------------
// Fused: dw 3x3x3 conv + BN1 + ReLU -> bf16 LDS tile -> MFMA pointwise GEMM
// + BN2 + ReLU -> out.
// Block: 256 thr, tile = 4(h) x 16(w) spatial at fixed (b,d) = 64 GEMM rows.
// Conv: thread (tx=cgroup 0..15, ty 0..15): rh=ty>>2, wq=ty&3 -> 4 w-adjacent
// outputs x 4 channels, 6-wide register sliding window, mask-multiply padding.
// GEMM: wave wv = rows wv*16+lrow (h=h0+wv, w=w0+row&15), full N=128, K=64.
// ---------------------------------------------------------------------------
__global__ __launch_bounds__(256) void fused_kernel(
    const float* __restrict__ x,
    const float* __restrict__ wgt,          // (3,3,3,1,64)
    const float* __restrict__ scale1,
    const float* __restrict__ shift1,
    const unsigned short* __restrict__ Wt,  // bf16 B-fragments (16 KB)
    const float* __restrict__ s2,
    const float* __restrict__ t2,
    float* __restrict__ out)
{
    __shared__ float wS[27 * 64];
    __shared__ float sS[64];
    __shared__ float tS[64];
    __shared__ unsigned short yS[64 * 72];  // 64 rows x 64 ch, +8 short pad

    int tid = threadIdx.x;
    for (int i = tid; i < 27 * 64; i += 256) wS[i] = wgt[i];
    if (tid < 64) { sS[tid] = scale1[tid]; tS[tid] = shift1[tid]; }
    __syncthreads();

    int w0 = blockIdx.x * 16;
    int h0 = blockIdx.y * 4;
    int bd = blockIdx.z;
    int b  = bd / 48;
    int d  = bd % 48;

    int tx = tid & 15;            // channel group
    int ty = tid >> 4;            // 0..15
    int c0 = tx * 4;
    int wq = ty & 3;
    int rh = ty >> 2;
    int w0t = w0 + wq * 4;        // base out-w of this thread's 4 outputs
    int h   = h0 + rh;

    float4 acc[4];
    #pragma unroll
    for (int r = 0; r < 4; ++r) acc[r] = make_float4(0.f, 0.f, 0.f, 0.f);

    // w-window masks (thread-invariant across dd/hh)
    float mw[6];
    #pragma unroll
    for (int p = 0; p < 6; ++p) {
        int zw = w0t - 1 + p;
        mw[p] = (zw >= 0 && zw < 48) ? 1.f : 0.f;
    }

    #pragma unroll
    for (int dd = 0; dd < 3; ++dd) {
        int zd = d + dd - 1;
        float md = (zd >= 0 && zd < 48) ? 1.f : 0.f;
        int zdc = min(max(zd, 0), 47);
        #pragma unroll
        for (int hh = 0; hh < 3; ++hh) {
            int zh = h + hh - 1;
            float mdh = (zh >= 0 && zh < 48) ? md : 0.f;
            int zhc = min(max(zh, 0), 47);
            const float* rowp = x + ((((long)b * 48 + zdc) * 48 + zhc) * 48) * 64 + c0;

            float4 xv[6];
            #pragma unroll
            for (int p = 0; p < 6; ++p) {
                int zw = w0t - 1 + p;
                int zwc = min(max(zw, 0), 47);
                xv[p] = *(const float4*)(rowp + zwc * 64);
            }
            #pragma unroll
            for (int p = 0; p < 6; ++p) {
                float m = mdh * mw[p];
                xv[p].x *= m; xv[p].y *= m; xv[p].z *= m; xv[p].w *= m;
            }
            #pragma unroll
            for (int ww = 0; ww < 3; ++ww) {
                const float4 wv = *(const float4*)(&wS[((dd * 3 + hh) * 3 + ww) * 64 + c0]);
                #pragma unroll
                for (int r = 0; r < 4; ++r) {
                    acc[r].x += xv[r + ww].x * wv.x;
                    acc[r].y += xv[r + ww].y * wv.y;
                    acc[r].z += xv[r + ww].z * wv.z;
                    acc[r].w += xv[r + ww].w * wv.w;
                }
            }
        }
    }

    // BN1 + ReLU + bf16 -> LDS (row = ty*4+r, padded stride 72 shorts)
    {
        float4 s = *(const float4*)(&sS[c0]);
        float4 t = *(const float4*)(&tS[c0]);
        #pragma unroll
        for (int r = 0; r < 4; ++r) {
            ushort4 o;
            o.x = f2bf(fmaxf(acc[r].x * s.x + t.x, 0.f));
            o.y = f2bf(fmaxf(acc[r].y * s.y + t.y, 0.f));
            o.z = f2bf(fmaxf(acc[r].z * s.z + t.z, 0.f));
            o.w = f2bf(fmaxf(acc[r].w * s.w + t.w, 0.f));
            *(ushort4*)(&yS[(ty * 4 + r) * 72 + c0]) = o;
        }
    }
    __syncthreads();

    // GEMM: 4 waves, wave = 16 rows x 128 cols, K=64 in 2 MFMA k-steps
    int wv   = tid >> 6;
    int lane = tid & 63;
    int lrow = lane & 15;
    int quad = lane >> 4;

    const short8 a0 = *(const short8*)(&yS[(wv * 16 + lrow) * 72 + quad * 8]);
    const short8 a1 = *(const short8*)(&yS[(wv * 16 + lrow) * 72 + 32 + quad * 8]);

    v4f g[8];
    #pragma unroll
    for (int n = 0; n < 8; ++n) g[n] = (v4f){0.f, 0.f, 0.f, 0.f};

    #pragma unroll
    for (int n = 0; n < 8; ++n) {
        short8 b0 = *(const short8*)(Wt + ((n * 2 + 0) * 64 + lane) * 8);
        short8 b1 = *(const short8*)(Wt + ((n * 2 + 1) * 64 + lane) * 8);
        g[n] = __builtin_amdgcn_mfma_f32_16x16x32_bf16(a0, b0, g[n], 0, 0, 0);
        g[n] = __builtin_amdgcn_mfma_f32_16x16x32_bf16(a1, b1, g[n], 0, 0, 0);
    }

    // BN2 + ReLU epilogue. D: col=lane&15, row=quad*4+reg.
    long base_out = ((((long)b * 48 + d) * 48 + (h0 + wv)) * 48 + w0) * 128;
    #pragma unroll
    for (int n = 0; n < 8; ++n) {
        int f = n * 16 + lrow;
        float sf = s2[f];
        float tf = t2[f];
        #pragma unroll
        for (int r = 0; r < 4; ++r) {
            float v = fmaxf(g[n][r] * sf + tf, 0.f);
            out[base_out + (quad * 4 + r) * 128 + f] = v;
        }
    }
}

// ---------------------------------------------------------------------------
extern "C" void kernel_launch(void* const* d_in, const int* in_sizes, int n_in,
                              void* d_out, int out_size, void* d_ws, size_t ws_size,
                              hipStream_t stream)
{
    const float* x   = (const float*)d_in[0];
    const float* dwk = (const float*)d_in[1];
    const float* dwb = (const float*)d_in[2];
    const float* g1  = (const float*)d_in[3];
    const float* b1  = (const float*)d_in[4];
    const float* m1  = (const float*)d_in[5];
    const float* v1  = (const float*)d_in[6];
    const float* pw  = (const float*)d_in[7];
    const float* pwb = (const float*)d_in[8];
    const float* g2  = (const float*)d_in[9];
    const float* b2  = (const float*)d_in[10];
    const float* m2  = (const float*)d_in[11];
    const float* v2  = (const float*)d_in[12];

    float* outp = (float*)d_out;

    // ws layout: [0..383] floats: scale1(64) shift1(64) s2(128) t2(128)
    //            byte 2048: Wt bf16[8192] (16 KB)
    float* scale1 = (float*)d_ws;
    float* shift1 = scale1 + 64;
    float* s2     = scale1 + 128;
    float* t2     = scale1 + 256;
    unsigned short* Wt = (unsigned short*)((char*)d_ws + 2048);

    hipLaunchKernelGGL(prep_kernel, dim3(32), dim3(256), 0, stream,
                       dwb, g1, b1, m1, v1, pw, pwb, g2, b2, m2, v2,
                       scale1, shift1, s2, t2, Wt);

    hipLaunchKernelGGL(fused_kernel, dim3(3, 12, 96), dim3(256), 0, stream,
                       x, dwk, scale1, shift1, Wt, s2, t2, outp);
}

// Round 3
// 216.888 us; speedup vs baseline: 1.1681x; 1.0219x over previous
//
#include <hip/hip_runtime.h>
#include <hip/hip_bf16.h>

#define EPS 1e-3f

typedef __attribute__((ext_vector_type(8))) short short8;
typedef __attribute__((ext_vector_type(4))) float v4f;

__device__ __forceinline__ unsigned short f2bf(float f) {
    unsigned int u = __float_as_uint(f);
    unsigned int r = (u + 0x7fffu + ((u >> 16) & 1u)) >> 16;
    return (unsigned short)r;
}

// ---------------------------------------------------------------------------
// Prep: fold biases + BN into per-channel affine; transpose pw_kernel into
// bf16 MFMA B-fragment layout: Wt[((ntile*2+kstep)*64 + lane)*8 + j] =
//   bf16(W[k = kstep*32 + (lane>>4)*8 + j][f = ntile*16 + (lane&15)])
// grid = 32 blocks x 256 thr; one Wt element per thread; block 0 does affines.
// ---------------------------------------------------------------------------
__global__ __launch_bounds__(256) void prep_kernel(
    const float* __restrict__ dwb,
    const float* __restrict__ g1, const float* __restrict__ b1,
    const float* __restrict__ m1, const float* __restrict__ v1,
    const float* __restrict__ pw, const float* __restrict__ pwb,
    const float* __restrict__ g2, const float* __restrict__ b2,
    const float* __restrict__ m2, const float* __restrict__ v2,
    float* __restrict__ scale1, float* __restrict__ shift1,
    float* __restrict__ s2, float* __restrict__ t2,
    unsigned short* __restrict__ Wt)
{
    int tid = threadIdx.x;
    if (blockIdx.x == 0) {
        if (tid < 64) {
            float inv = g1[tid] * rsqrtf(v1[tid] + EPS);
            scale1[tid] = inv;
            shift1[tid] = dwb[tid] * inv + b1[tid] - m1[tid] * inv;
        }
        if (tid < 128) {
            float inv = g2[tid] * rsqrtf(v2[tid] + EPS);
            s2[tid] = inv;
            t2[tid] = pwb[tid] * inv + b2[tid] - m2[tid] * inv;
        }
    }
    int idx = blockIdx.x * 256 + tid;      // 0..8191
    int j     = idx & 7;
    int lane  = (idx >> 3) & 63;
    int kstep = (idx >> 9) & 1;
    int ntile = idx >> 10;                 // 0..7
    int k = kstep * 32 + (lane >> 4) * 8 + j;
    int f = ntile * 16 + (lane & 15);
    Wt[idx] = f2bf(pw[k * 128 + f]);
}

// ---------------------------------------------------------------------------
// Fused: dw 3x3x3 conv + BN1 + ReLU -> bf16 LDS tile -> MFMA pointwise GEMM
// + BN2 + ReLU -> out.
// Block: 256 thr, tile = 4(h) x 16(w) spatial at fixed (b,d) = 64 GEMM rows.
// Conv: thread (tx=cgroup, ty): 4 w-adjacent outputs x 4 channels.
// ILP: entire d-slab (3h x 6w = 18 float4) loaded as one batch so ~18 loads
// are in flight per thread (was 6 -> latency-bound at 87us).
// GEMM: wave wv = rows wv*16+lrow (h=h0+wv, w=w0+row&15), full N=128, K=64.
// ---------------------------------------------------------------------------
__global__ __launch_bounds__(256) void fused_kernel(
    const float* __restrict__ x,
    const float* __restrict__ wgt,          // (3,3,3,1,64)
    const float* __restrict__ scale1,
    const float* __restrict__ shift1,
    const unsigned short* __restrict__ Wt,  // bf16 B-fragments (16 KB)
    const float* __restrict__ s2,
    const float* __restrict__ t2,
    float* __restrict__ out)
{
    __shared__ float wS[27 * 64];
    __shared__ float sS[64];
    __shared__ float tS[64];
    __shared__ unsigned short yS[64 * 72];  // 64 rows x 64 ch, +8 short pad

    int tid = threadIdx.x;
    for (int i = tid; i < 27 * 64; i += 256) wS[i] = wgt[i];
    if (tid < 64) { sS[tid] = scale1[tid]; tS[tid] = shift1[tid]; }
    __syncthreads();

    int w0 = blockIdx.x * 16;
    int h0 = blockIdx.y * 4;
    int bd = blockIdx.z;
    int b  = bd / 48;
    int d  = bd % 48;

    int tx = tid & 15;            // channel group
    int ty = tid >> 4;            // 0..15
    int c0 = tx * 4;
    int wq = ty & 3;
    int rh = ty >> 2;
    int w0t = w0 + wq * 4;        // base out-w of this thread's 4 outputs
    int h   = h0 + rh;

    float4 acc[4];
    #pragma unroll
    for (int r = 0; r < 4; ++r) acc[r] = make_float4(0.f, 0.f, 0.f, 0.f);

    // precomputed masks + clamped indices (thread-invariant across dd)
    float mw[6];
    int   wcl[6];
    #pragma unroll
    for (int p = 0; p < 6; ++p) {
        int zw = w0t - 1 + p;
        mw[p]  = (zw >= 0 && zw < 48) ? 1.f : 0.f;
        wcl[p] = min(max(zw, 0), 47) * 64;
    }
    float mh[3];
    int   hcl[3];
    #pragma unroll
    for (int hh = 0; hh < 3; ++hh) {
        int zh = h + hh - 1;
        mh[hh]  = (zh >= 0 && zh < 48) ? 1.f : 0.f;
        hcl[hh] = min(max(zh, 0), 47) * 48 * 64;
    }

    #pragma unroll
    for (int dd = 0; dd < 3; ++dd) {
        int zd = d + dd - 1;
        float md = (zd >= 0 && zd < 48) ? 1.f : 0.f;
        int zdc = min(max(zd, 0), 47);
        const float* dp = x + (((long)b * 48 + zdc) * 48 * 48) * 64 + c0;

        // one 18-deep load batch for the whole d-slab
        float4 xv[3][6];
        #pragma unroll
        for (int hh = 0; hh < 3; ++hh) {
            const float* rowp = dp + hcl[hh];
            #pragma unroll
            for (int p = 0; p < 6; ++p)
                xv[hh][p] = *(const float4*)(rowp + wcl[p]);
        }
        // mask
        #pragma unroll
        for (int hh = 0; hh < 3; ++hh) {
            float mdh = md * mh[hh];
            #pragma unroll
            for (int p = 0; p < 6; ++p) {
                float m = mdh * mw[p];
                xv[hh][p].x *= m; xv[hh][p].y *= m;
                xv[hh][p].z *= m; xv[hh][p].w *= m;
            }
        }
        // FMA
        #pragma unroll
        for (int hh = 0; hh < 3; ++hh) {
            #pragma unroll
            for (int ww = 0; ww < 3; ++ww) {
                const float4 wv = *(const float4*)(&wS[((dd * 3 + hh) * 3 + ww) * 64 + c0]);
                #pragma unroll
                for (int r = 0; r < 4; ++r) {
                    acc[r].x += xv[hh][r + ww].x * wv.x;
                    acc[r].y += xv[hh][r + ww].y * wv.y;
                    acc[r].z += xv[hh][r + ww].z * wv.z;
                    acc[r].w += xv[hh][r + ww].w * wv.w;
                }
            }
        }
    }

    // BN1 + ReLU + bf16 -> LDS (row = ty*4+r, padded stride 72 shorts)
    {
        float4 s = *(const float4*)(&sS[c0]);
        float4 t = *(const float4*)(&tS[c0]);
        #pragma unroll
        for (int r = 0; r < 4; ++r) {
            ushort4 o;
            o.x = f2bf(fmaxf(acc[r].x * s.x + t.x, 0.f));
            o.y = f2bf(fmaxf(acc[r].y * s.y + t.y, 0.f));
            o.z = f2bf(fmaxf(acc[r].z * s.z + t.z, 0.f));
            o.w = f2bf(fmaxf(acc[r].w * s.w + t.w, 0.f));
            *(ushort4*)(&yS[(ty * 4 + r) * 72 + c0]) = o;
        }
    }
    __syncthreads();

    // GEMM: 4 waves, wave = 16 rows x 128 cols, K=64 in 2 MFMA k-steps
    int wv   = tid >> 6;
    int lane = tid & 63;
    int lrow = lane & 15;
    int quad = lane >> 4;

    const short8 a0 = *(const short8*)(&yS[(wv * 16 + lrow) * 72 + quad * 8]);
    const short8 a1 = *(const short8*)(&yS[(wv * 16 + lrow) * 72 + 32 + quad * 8]);

    v4f g[8];
    #pragma unroll
    for (int n = 0; n < 8; ++n) g[n] = (v4f){0.f, 0.f, 0.f, 0.f};

    #pragma unroll
    for (int n = 0; n < 8; ++n) {
        short8 b0 = *(const short8*)(Wt + ((n * 2 + 0) * 64 + lane) * 8);
        short8 b1 = *(const short8*)(Wt + ((n * 2 + 1) * 64 + lane) * 8);
        g[n] = __builtin_amdgcn_mfma_f32_16x16x32_bf16(a0, b0, g[n], 0, 0, 0);
        g[n] = __builtin_amdgcn_mfma_f32_16x16x32_bf16(a1, b1, g[n], 0, 0, 0);
    }

    // BN2 + ReLU epilogue. D: col=lane&15, row=quad*4+reg.
    long base_out = ((((long)b * 48 + d) * 48 + (h0 + wv)) * 48 + w0) * 128;
    #pragma unroll
    for (int n = 0; n < 8; ++n) {
        int f = n * 16 + lrow;
        float sf = s2[f];
        float tf = t2[f];
        #pragma unroll
        for (int r = 0; r < 4; ++r) {
            float v = fmaxf(g[n][r] * sf + tf, 0.f);
            __builtin_nontemporal_store(v, &out[base_out + (quad * 4 + r) * 128 + f]);
        }
    }
}

// ---------------------------------------------------------------------------
extern "C" void kernel_launch(void* const* d_in, const int* in_sizes, int n_in,
                              void* d_out, int out_size, void* d_ws, size_t ws_size,
                              hipStream_t stream)
{
    const float* x   = (const float*)d_in[0];
    const float* dwk = (const float*)d_in[1];
    const float* dwb = (const float*)d_in[2];
    const float* g1  = (const float*)d_in[3];
    const float* b1  = (const float*)d_in[4];
    const float* m1  = (const float*)d_in[5];
    const float* v1  = (const float*)d_in[6];
    const float* pw  = (const float*)d_in[7];
    const float* pwb = (const float*)d_in[8];
    const float* g2  = (const float*)d_in[9];
    const float* b2  = (const float*)d_in[10];
    const float* m2  = (const float*)d_in[11];
    const float* v2  = (const float*)d_in[12];

    float* outp = (float*)d_out;

    // ws layout: [0..383] floats: scale1(64) shift1(64) s2(128) t2(128)
    //            byte 2048: Wt bf16[8192] (16 KB)
    float* scale1 = (float*)d_ws;
    float* shift1 = scale1 + 64;
    float* s2     = scale1 + 128;
    float* t2     = scale1 + 256;
    unsigned short* Wt = (unsigned short*)((char*)d_ws + 2048);

    hipLaunchKernelGGL(prep_kernel, dim3(32), dim3(256), 0, stream,
                       dwb, g1, b1, m1, v1, pw, pwb, g2, b2, m2, v2,
                       scale1, shift1, s2, t2, Wt);

    hipLaunchKernelGGL(fused_kernel, dim3(3, 12, 96), dim3(256), 0, stream,
                       x, dwk, scale1, shift1, Wt, s2, t2, outp);
}

// Round 4
// 211.755 us; speedup vs baseline: 1.1965x; 1.0242x over previous
//
#include <hip/hip_runtime.h>
#include <hip/hip_bf16.h>

#define EPS 1e-3f

typedef __attribute__((ext_vector_type(8))) short short8;
typedef __attribute__((ext_vector_type(4))) float v4f;

__device__ __forceinline__ unsigned short f2bf(float f) {
    unsigned int u = __float_as_uint(f);
    unsigned int r = (u + 0x7fffu + ((u >> 16) & 1u)) >> 16;
    return (unsigned short)r;
}

// ---------------------------------------------------------------------------
// Prep: fold biases + BN into per-channel affine; transpose pw_kernel into
// bf16 MFMA B-fragment layout.
// ---------------------------------------------------------------------------
__global__ __launch_bounds__(256) void prep_kernel(
    const float* __restrict__ dwb,
    const float* __restrict__ g1, const float* __restrict__ b1,
    const float* __restrict__ m1, const float* __restrict__ v1,
    const float* __restrict__ pw, const float* __restrict__ pwb,
    const float* __restrict__ g2, const float* __restrict__ b2,
    const float* __restrict__ m2, const float* __restrict__ v2,
    float* __restrict__ scale1, float* __restrict__ shift1,
    float* __restrict__ s2, float* __restrict__ t2,
    unsigned short* __restrict__ Wt)
{
    int tid = threadIdx.x;
    if (blockIdx.x == 0) {
        if (tid < 64) {
            float inv = g1[tid] * rsqrtf(v1[tid] + EPS);
            scale1[tid] = inv;
            shift1[tid] = dwb[tid] * inv + b1[tid] - m1[tid] * inv;
        }
        if (tid < 128) {
            float inv = g2[tid] * rsqrtf(v2[tid] + EPS);
            s2[tid] = inv;
            t2[tid] = pwb[tid] * inv + b2[tid] - m2[tid] * inv;
        }
    }
    int idx = blockIdx.x * 256 + tid;      // 0..8191
    int j     = idx & 7;
    int lane  = (idx >> 3) & 63;
    int kstep = (idx >> 9) & 1;
    int ntile = idx >> 10;                 // 0..7
    int k = kstep * 32 + (lane >> 4) * 8 + j;
    int f = ntile * 16 + (lane & 15);
    Wt[idx] = f2bf(pw[k * 128 + f]);
}

// ---------------------------------------------------------------------------
// Fused: dw 3x3x3 conv + BN1 + ReLU -> bf16 LDS tile -> MFMA pointwise GEMM
// + BN2 + ReLU -> out.
// Block: 256 thr, tile = 4(h) x 16(w) at fixed (b,d) = 64 GEMM rows.
// Boundary handling: d-mask block-uniform branch, h-mask wave-uniform branch
// (rh == wave id), w-edge only window positions 0 and 5 -> 2 masked muls.
// XCD swizzle: each XCD owns a contiguous 12-wide bd range so d-halo slabs
// are L2-shared.
// ---------------------------------------------------------------------------
__global__ __launch_bounds__(256) void fused_kernel(
    const float* __restrict__ x,
    const float* __restrict__ wgt,          // (3,3,3,1,64)
    const float* __restrict__ scale1,
    const float* __restrict__ shift1,
    const unsigned short* __restrict__ Wt,  // bf16 B-fragments (16 KB)
    const float* __restrict__ s2,
    const float* __restrict__ t2,
    float* __restrict__ out)
{
    __shared__ float wS[27 * 64];
    __shared__ float sS[64];
    __shared__ float tS[64];
    __shared__ unsigned short yS[64 * 72];  // 64 rows x 64 ch, +8 short pad

    int tid = threadIdx.x;
    for (int i = tid; i < 27 * 64; i += 256) wS[i] = wgt[i];
    if (tid < 64) { sS[tid] = scale1[tid]; tS[tid] = shift1[tid]; }
    __syncthreads();

    // XCD-aware decode: xcd = n&7 owns bd in [xcd*12, xcd*12+12)
    int n   = blockIdx.x;
    int xcd = n & 7;
    int j   = n >> 3;              // 0..431
    int bd  = xcd * 12 + (j % 12); // 0..95
    int s   = j / 12;              // 0..35
    int w0  = (s % 3) * 16;
    int h0  = (s / 3) * 4;
    int b   = bd / 48;
    int d   = bd % 48;

    int tx = tid & 15;            // channel group
    int ty = tid >> 4;            // 0..15
    int c0 = tx * 4;
    int wq = ty & 3;
    int rh = ty >> 2;             // == wave id -> h is wave-uniform
    int w0t = w0 + wq * 4;        // base out-w of this thread's 4 outputs
    int h   = h0 + rh;

    float4 acc[4];
    #pragma unroll
    for (int r = 0; r < 4; ++r) acc[r] = make_float4(0.f, 0.f, 0.f, 0.f);

    // w-edge masks: only window positions 0 and 5 can be out of range
    float mwL = (w0t >= 1)  ? 1.f : 0.f;   // p=0 (zw = w0t-1)
    float mwR = (w0t <= 43) ? 1.f : 0.f;   // p=5 (zw = w0t+4)
    int wcl[6];
    #pragma unroll
    for (int p = 0; p < 6; ++p)
        wcl[p] = min(max(w0t - 1 + p, 0), 47) * 64;

    bool hok[3];
    int  hcl[3];
    #pragma unroll
    for (int hh = 0; hh < 3; ++hh) {
        int zh = h + hh - 1;
        hok[hh] = (zh >= 0 && zh < 48);
        hcl[hh] = min(max(zh, 0), 47) * 48 * 64;
    }

    #pragma unroll
    for (int dd = 0; dd < 3; ++dd) {
        int zd = d + dd - 1;
        bool dok = (zd >= 0 && zd < 48);          // block-uniform
        int zdc = min(max(zd, 0), 47);
        const float* dp = x + (((long)b * 48 + zdc) * 48 * 48) * 64 + c0;

        // one 18-deep unconditional load batch (clamped addresses)
        float4 xv[3][6];
        #pragma unroll
        for (int hh = 0; hh < 3; ++hh) {
            const float* rowp = dp + hcl[hh];
            #pragma unroll
            for (int p = 0; p < 6; ++p)
                xv[hh][p] = *(const float4*)(rowp + wcl[p]);
        }

        if (dok) {                                 // uniform branch
            #pragma unroll
            for (int hh = 0; hh < 3; ++hh) {
                if (hok[hh]) {                     // wave-uniform branch
                    // w-edge masking: only p=0 / p=5
                    xv[hh][0].x *= mwL; xv[hh][0].y *= mwL;
                    xv[hh][0].z *= mwL; xv[hh][0].w *= mwL;
                    xv[hh][5].x *= mwR; xv[hh][5].y *= mwR;
                    xv[hh][5].z *= mwR; xv[hh][5].w *= mwR;
                    #pragma unroll
                    for (int ww = 0; ww < 3; ++ww) {
                        const float4 wv = *(const float4*)(&wS[((dd * 3 + hh) * 3 + ww) * 64 + c0]);
                        #pragma unroll
                        for (int r = 0; r < 4; ++r) {
                            acc[r].x += xv[hh][r + ww].x * wv.x;
                            acc[r].y += xv[hh][r + ww].y * wv.y;
                            acc[r].z += xv[hh][r + ww].z * wv.z;
                            acc[r].w += xv[hh][r + ww].w * wv.w;
                        }
                    }
                }
            }
        }
    }

    // BN1 + ReLU + bf16 -> LDS (row = ty*4+r, padded stride 72 shorts)
    {
        float4 s1 = *(const float4*)(&sS[c0]);
        float4 t1 = *(const float4*)(&tS[c0]);
        #pragma unroll
        for (int r = 0; r < 4; ++r) {
            ushort4 o;
            o.x = f2bf(fmaxf(acc[r].x * s1.x + t1.x, 0.f));
            o.y = f2bf(fmaxf(acc[r].y * s1.y + t1.y, 0.f));
            o.z = f2bf(fmaxf(acc[r].z * s1.z + t1.z, 0.f));
            o.w = f2bf(fmaxf(acc[r].w * s1.w + t1.w, 0.f));
            *(ushort4*)(&yS[(ty * 4 + r) * 72 + c0]) = o;
        }
    }
    __syncthreads();

    // GEMM: 4 waves, wave = 16 rows x 128 cols, K=64 in 2 MFMA k-steps
    int wv   = tid >> 6;
    int lane = tid & 63;
    int lrow = lane & 15;
    int quad = lane >> 4;

    const short8 a0 = *(const short8*)(&yS[(wv * 16 + lrow) * 72 + quad * 8]);
    const short8 a1 = *(const short8*)(&yS[(wv * 16 + lrow) * 72 + 32 + quad * 8]);

    v4f g[8];
    #pragma unroll
    for (int nn = 0; nn < 8; ++nn) g[nn] = (v4f){0.f, 0.f, 0.f, 0.f};

    #pragma unroll
    for (int nn = 0; nn < 8; ++nn) {
        short8 b0 = *(const short8*)(Wt + ((nn * 2 + 0) * 64 + lane) * 8);
        short8 b1 = *(const short8*)(Wt + ((nn * 2 + 1) * 64 + lane) * 8);
        g[nn] = __builtin_amdgcn_mfma_f32_16x16x32_bf16(a0, b0, g[nn], 0, 0, 0);
        g[nn] = __builtin_amdgcn_mfma_f32_16x16x32_bf16(a1, b1, g[nn], 0, 0, 0);
    }

    // BN2 + ReLU epilogue. D: col=lane&15, row=quad*4+reg.
    long base_out = ((((long)b * 48 + d) * 48 + (h0 + wv)) * 48 + w0) * 128;
    #pragma unroll
    for (int nn = 0; nn < 8; ++nn) {
        int f = nn * 16 + lrow;
        float sf = s2[f];
        float tf = t2[f];
        #pragma unroll
        for (int r = 0; r < 4; ++r) {
            float v = fmaxf(g[nn][r] * sf + tf, 0.f);
            out[base_out + (quad * 4 + r) * 128 + f] = v;
        }
    }
}

// ---------------------------------------------------------------------------
extern "C" void kernel_launch(void* const* d_in, const int* in_sizes, int n_in,
                              void* d_out, int out_size, void* d_ws, size_t ws_size,
                              hipStream_t stream)
{
    const float* x   = (const float*)d_in[0];
    const float* dwk = (const float*)d_in[1];
    const float* dwb = (const float*)d_in[2];
    const float* g1  = (const float*)d_in[3];
    const float* b1  = (const float*)d_in[4];
    const float* m1  = (const float*)d_in[5];
    const float* v1  = (const float*)d_in[6];
    const float* pw  = (const float*)d_in[7];
    const float* pwb = (const float*)d_in[8];
    const float* g2  = (const float*)d_in[9];
    const float* b2  = (const float*)d_in[10];
    const float* m2  = (const float*)d_in[11];
    const float* v2  = (const float*)d_in[12];

    float* outp = (float*)d_out;

    float* scale1 = (float*)d_ws;
    float* shift1 = scale1 + 64;
    float* s2     = scale1 + 128;
    float* t2     = scale1 + 256;
    unsigned short* Wt = (unsigned short*)((char*)d_ws + 2048);

    hipLaunchKernelGGL(prep_kernel, dim3(32), dim3(256), 0, stream,
                       dwb, g1, b1, m1, v1, pw, pwb, g2, b2, m2, v2,
                       scale1, shift1, s2, t2, Wt);

    hipLaunchKernelGGL(fused_kernel, dim3(3456), dim3(256), 0, stream,
                       x, dwk, scale1, shift1, Wt, s2, t2, outp);
}